// Round 5
// baseline (524.637 us; speedup 1.0000x reference)
//
#include <hip/hip_runtime.h>

typedef unsigned short u16;
typedef __attribute__((ext_vector_type(8))) unsigned short v8u16;
typedef __attribute__((ext_vector_type(4))) unsigned short v4u16;
typedef __attribute__((ext_vector_type(8))) __bf16 v8bf;
typedef __attribute__((ext_vector_type(4))) float v4f;

#define NN 50000
#define EE 150000
#define SCAN_CHUNK 512
#define NB_PER_SET 98   // ceil(NN / SCAN_CHUNK)

__device__ inline float b2f(u16 u) {
    union { unsigned int i; float f; } x; x.i = ((unsigned int)u) << 16; return x.f;
}
__device__ inline u16 f2b(float f) {
    union { float f; unsigned int i; } x; x.f = f;
    unsigned int r = x.i + 0x7FFFu + ((x.i >> 16) & 1u);
    return (u16)(r >> 16);
}
__device__ inline float wred(float v) {
    v += __shfl_down(v, 32, 64);
    v += __shfl_down(v, 16, 64);
    v += __shfl_down(v, 8, 64);
    v += __shfl_down(v, 4, 64);
    v += __shfl_down(v, 2, 64);
    v += __shfl_down(v, 1, 64);
    return v;
}
__device__ inline int wred_i(int v) {
    v += __shfl_down(v, 32, 64);
    v += __shfl_down(v, 16, 64);
    v += __shfl_down(v, 8, 64);
    v += __shfl_down(v, 4, 64);
    v += __shfl_down(v, 2, 64);
    v += __shfl_down(v, 1, 64);
    return v;
}

// async global->LDS, 16B per lane; LDS dest is wave-uniform base + lane*16
__device__ __forceinline__ void gll16(const u16* g, u16* l) {
    __builtin_amdgcn_global_load_lds(
        (const __attribute__((address_space(1))) void*)g,
        (__attribute__((address_space(3))) void*)l, 16, 0, 0);
}

// ---------------- fused weight prep ----------------

__global__ void transpose4(const float* __restrict__ W0, u16* __restrict__ T0,
                           const float* __restrict__ W1, u16* __restrict__ T1,
                           const float* __restrict__ W2, u16* __restrict__ T2,
                           const float* __restrict__ W3, u16* __restrict__ T3) {
    int idx = blockIdx.x * blockDim.x + threadIdx.x;
    const float* W; u16* T; int N, K, base;
    if (idx < 262144)      { W = W0; T = T0; K = 512; N = 512; base = 0; }
    else if (idx < 524288) { W = W1; T = T1; K = 512; N = 512; base = 262144; }
    else if (idx < 655360) { W = W2; T = T2; K = 512; N = 256; base = 524288; }
    else if (idx < 720896) { W = W3; T = T3; K = 256; N = 256; base = 655360; }
    else return;
    int i = idx - base;
    int n = i % N, k = i / N;
    T[(size_t)n * K + k] = f2b(W[i]);
}

__global__ void wv4(const float* __restrict__ Wa, const float* __restrict__ Wb,
                    const float* __restrict__ Wc, const float* __restrict__ Wd,
                    const float* __restrict__ aa, const float* __restrict__ ab,
                    const float* __restrict__ ac, const float* __restrict__ ad,
                    float* __restrict__ vbuf) {
    int rw = (blockIdx.x * blockDim.x + threadIdx.x) >> 6;  // 0..2047
    int lane = threadIdx.x & 63;
    if (rw >= 2048) return;
    int seg = rw >> 9, r = rw & 511;
    const float* W; const float* a; int C;
    if (seg == 0)      { W = Wa; a = aa; C = 512; }
    else if (seg == 1) { W = Wb; a = ab; C = 512; }
    else if (seg == 2) { W = Wc; a = ac; C = 256; }
    else               { W = Wd; a = ad; C = 256; }
    float s = 0.f;
    int c0 = lane * 8;
    if (c0 < C) {
        const float* wp = W + (size_t)r * C + c0;
        v4f w0 = *(const v4f*)wp;
        v4f w1 = *(const v4f*)(wp + 4);
        v4f a0 = *(const v4f*)(a + c0);
        v4f a1 = *(const v4f*)(a + c0 + 4);
#pragma unroll
        for (int j = 0; j < 4; ++j) s += w0[j] * a0[j] + w1[j] * a1[j];
    }
    s = wred(s);
    if (lane == 0) vbuf[rw] = s;
}

// asrc/adst GEMV pair + bf16 downcast of x (one wave per node, D=512)
__global__ void alpha_pair_f32x(const float* __restrict__ X, const float* __restrict__ vs,
                                const float* __restrict__ vd, float* __restrict__ as_,
                                float* __restrict__ ad_, u16* __restrict__ Xb, int Nn) {
    int w = (blockIdx.x * blockDim.x + threadIdx.x) >> 6;
    int lane = threadIdx.x & 63;
    if (w >= Nn) return;
    const float* xp = X + (size_t)w * 512 + lane * 8;
    v4f x0 = *(const v4f*)xp;
    v4f x1 = *(const v4f*)(xp + 4);
    const float* vsp = vs + lane * 8;
    const float* vdp = vd + lane * 8;
    float s1 = 0.f, s2 = 0.f;
    v8u16 o;
#pragma unroll
    for (int j = 0; j < 4; ++j) {
        s1 += x0[j] * vsp[j] + x1[j] * vsp[j + 4];
        s2 += x0[j] * vdp[j] + x1[j] * vdp[j + 4];
        o[j] = f2b(x0[j]); o[j + 4] = f2b(x1[j]);
    }
    *(v8u16*)(Xb + (size_t)w * 512 + lane * 8) = o;
    s1 = wred(s1);
    s2 = wred(s2);
    if (lane == 0) { as_[w] = s1; ad_[w] = s2; }
}

// ---------------- CSR build, both edge sets fused ----------------

__global__ void deg2_kernel(const int* __restrict__ ei1, const int* __restrict__ ei2,
                            int* __restrict__ deg) {
    int idx = blockIdx.x * blockDim.x + threadIdx.x;
    if (idx >= 2 * EE) return;
    int set = idx >= EE;
    int e = idx - set * EE;
    const int* ei = set ? ei2 : ei1;
    atomicAdd(&deg[set * NN + ei[EE + e]], 1);
}

// multi-block exclusive scan of deg (2 independent segments of NN) -> rp
// pass 1: per-block (512-elem chunk) sums
__global__ void scan_partial(const int* __restrict__ deg, int* __restrict__ bsum) {
    int b = blockIdx.x;                       // 0..2*NB_PER_SET-1
    int set = b / NB_PER_SET, lb = b - set * NB_PER_SET;
    int tid = threadIdx.x;                    // 256
    int i0 = lb * SCAN_CHUNK + tid * 2;
    int s = 0;
    if (i0 < NN)     s += deg[set * NN + i0];
    if (i0 + 1 < NN) s += deg[set * NN + i0 + 1];
    s = wred_i(s);
    __shared__ int lsum[4];
    if ((tid & 63) == 0) lsum[tid >> 6] = s;
    __syncthreads();
    if (tid == 0) bsum[b] = lsum[0] + lsum[1] + lsum[2] + lsum[3];
}

// pass 2: one block; exclusive scan of the 98 block sums within each set
__global__ void scan_tops(int* __restrict__ bsum) {
    __shared__ int ls[256];
    int tid = threadIdx.x;                    // 256 = 2 sets x 128 slots
    int set = tid >> 7, lb = tid & 127;
    int v = (lb < NB_PER_SET) ? bsum[set * NB_PER_SET + lb] : 0;
    ls[tid] = v;
    __syncthreads();
    for (int off = 1; off < 128; off <<= 1) {
        int t = (lb >= off) ? ls[tid - off] : 0;
        __syncthreads();
        ls[tid] += t;
        __syncthreads();
    }
    if (lb < NB_PER_SET) bsum[set * NB_PER_SET + lb] = ls[tid] - v;  // exclusive
}

// pass 3: per-block local exclusive scan + block offset -> rp
__global__ void scan_final(const int* __restrict__ deg, const int* __restrict__ bsum,
                           int* __restrict__ rp) {
    int b = blockIdx.x;
    int set = b / NB_PER_SET, lb = b - set * NB_PER_SET;
    int tid = threadIdx.x;                    // 256
    int i0 = lb * SCAN_CHUNK + tid * 2;
    int d0 = (i0 < NN)     ? deg[set * NN + i0]     : 0;
    int d1 = (i0 + 1 < NN) ? deg[set * NN + i0 + 1] : 0;
    int pair = d0 + d1;
    __shared__ int ps[256];
    ps[tid] = pair;
    __syncthreads();
    for (int off = 1; off < 256; off <<= 1) {
        int t = (tid >= off) ? ps[tid - off] : 0;
        __syncthreads();
        ps[tid] += t;
        __syncthreads();
    }
    int base = bsum[b] + ps[tid] - pair;      // exclusive over this block's pairs
    if (i0 < NN)     rp[set * (NN + 1) + i0] = base;
    if (i0 + 1 < NN) rp[set * (NN + 1) + i0 + 1] = base + d0;
    if (b == 0 && tid == 0) { rp[NN] = EE; rp[(NN + 1) + NN] = EE; }
}

// fill permuted edge arrays; consumes deg via atomicSub (no cursor/memset needed)
__global__ void fill2_kernel(const int* __restrict__ ei1, const int* __restrict__ ei2,
                             const int* __restrict__ rp, int* __restrict__ deg,
                             int* __restrict__ srcp, int* __restrict__ dstp) {
    int idx = blockIdx.x * blockDim.x + threadIdx.x;
    if (idx >= 2 * EE) return;
    int set = idx >= EE;
    int e = idx - set * EE;
    const int* ei = set ? ei2 : ei1;
    int d = ei[EE + e];
    int old = atomicSub(&deg[set * NN + d], 1);
    int pos = rp[set * (NN + 1) + d] + old - 1;
    srcp[set * EE + pos] = ei[e];
    dstp[set * EE + pos] = d;
}

// per-layer edge weights: ex[i] = exp(leaky(asrc[src]+adst[dst])), both sets
__global__ void edge_ex(const int* __restrict__ srcp, const int* __restrict__ dstp,
                        const float* __restrict__ asrc, const float* __restrict__ adst,
                        float* __restrict__ ex) {
    int i = blockIdx.x * blockDim.x + threadIdx.x;
    if (i >= 2 * EE) return;
    float t = asrc[srcp[i]] + adst[dstp[i]];
    t = t > 0.f ? t : 0.2f * t;
    ex[i] = __expf(fminf(t, 60.f));
}

// ---------------- pull aggregate: one wave per dst node, single pass/set ----------------
template <int CV>
__global__ void gat_pull(const int* __restrict__ rp, const int* __restrict__ srcp,
                         const float* __restrict__ ex, const u16* __restrict__ H,
                         const float* __restrict__ bias, u16* __restrict__ G, int Nn) {
    const int C = CV * 64;
    int d = (blockIdx.x * blockDim.x + threadIdx.x) >> 6;
    int lane = threadIdx.x & 63;
    if (d >= Nn) return;
    float out[CV];
#pragma unroll
    for (int j = 0; j < CV; ++j) out[j] = 0.f;
#pragma unroll
    for (int set = 0; set < 2; ++set) {
        const int* rpS = rp + set * (NN + 1);
        int base = set * EE;
        int beg = rpS[d], end = rpS[d + 1];
        float acc[CV];
#pragma unroll
        for (int j = 0; j < CV; ++j) acc[j] = 0.f;
        float ssum = 0.f;
        for (int i = beg; i < end; ++i) {
            float w = ex[base + i];
            int s = srcp[base + i];
            ssum += w;
            const u16* hp = H + (size_t)s * C + lane * CV;
            if constexpr (CV == 8) {
                v8u16 hv = *(const v8u16*)hp;
#pragma unroll
                for (int j = 0; j < 8; ++j) acc[j] += w * b2f(hv[j]);
            } else {
                v4u16 hv = *(const v4u16*)hp;
#pragma unroll
                for (int j = 0; j < 4; ++j) acc[j] += w * b2f(hv[j]);
            }
        }
        float inv = 1.f / (ssum + 1e-16f);
#pragma unroll
        for (int j = 0; j < CV; ++j) out[j] += acc[j] * inv;
    }
    const float* bp = bias + lane * CV;
    u16* gp = G + (size_t)d * C + lane * CV;
    if constexpr (CV == 8) {
        v8u16 o;
#pragma unroll
        for (int j = 0; j < 8; ++j) o[j] = f2b(out[j] + 2.f * bp[j]);
        *(v8u16*)gp = o;
    } else {
        v4u16 o;
#pragma unroll
        for (int j = 0; j < 4; ++j) o[j] = f2b(out[j] + 2.f * bp[j]);
        *(v4u16*)gp = o;
    }
}

// ---------------- MFMA GEMM: 128x128 tile, BK=32, DOUBLE-buffered with
// COUNTED vmcnt (T4): loads stay in flight across raw s_barriers (no vmcnt(0)
// drain in the main loop). 32 KB LDS -> ~5 blocks/CU for TLP latency hiding.
// global_load_lds width=16, linear LDS dest; bijective chunked XCD swizzle.
// C[M,N] = A[M,K] @ Bt[N,K]^T. bf16 in, fp32 accum; out bf16 or fp32; bias/relu.
// Optional fused per-row alpha dots: aout_s[row] += sum_col v*avs[col], same d.
__global__ __launch_bounds__(256, 4) void gemm_bf16(
    const u16* __restrict__ A, const u16* __restrict__ Bt, void* __restrict__ Cv,
    int M, int N, int K, const float* __restrict__ bias, int relu, int outf32,
    const float* __restrict__ avs, const float* __restrict__ avd,
    float* __restrict__ aout_s, float* __restrict__ aout_d) {
    __shared__ u16 As[2][128 * 32];   // linear [row][32], 8 KB per buffer
    __shared__ u16 Bs[2][128 * 32];
    const int tid = threadIdx.x;
    const int lane = tid & 63;
    const int wid = tid >> 6;
    const int wm = wid >> 1;
    const int wn = wid & 1;
    const int quad = lane >> 4;
    const int l16 = lane & 15;

    // bijective chunked XCD swizzle: consecutive wg (sharing an A-panel) land
    // on the SAME XCD's L2 (verified: FETCH 101->29.6 MB).
    const int nwg = gridDim.x * gridDim.y;
    const int orig = blockIdx.y * gridDim.x + blockIdx.x;
    const int q = nwg >> 3, r = nwg & 7;
    const int xcd = orig & 7, loc = orig >> 3;
    const int wg = (xcd < r ? xcd * (q + 1) : r * (q + 1) + (xcd - r) * q) + loc;
    const int tileM = (wg / gridDim.x) * 128;
    const int tileN = (wg % gridDim.x) * 128;

    // staging: thread t loads 16B at (row = t>>2, col = (t&3)*8), inst 0 rows
    // 0..63, inst 1 rows 64..127; LDS is linear in t (gll16 requirement).
    const int srow = tid >> 2;
    const int scol = (tid & 3) * 8;
    int ra0 = tileM + srow;       if (ra0 >= M) ra0 = M - 1;
    int ra1 = tileM + 64 + srow;  if (ra1 >= M) ra1 = M - 1;
    const u16* gA0 = A + (size_t)ra0 * K + scol;
    const u16* gA1 = A + (size_t)ra1 * K + scol;
    const u16* gB0 = Bt + (size_t)(tileN + srow) * K + scol;
    const u16* gB1 = Bt + (size_t)(tileN + 64 + srow) * K + scol;

    v4f acc[4][4];
#pragma unroll
    for (int i = 0; i < 4; ++i)
#pragma unroll
        for (int j = 0; j < 4; ++j) acc[i][j] = v4f{0.f, 0.f, 0.f, 0.f};

    const int nt = K >> 5;
    // prologue: stage tile 0 into buf 0 (4 loads in flight)
    gll16(gA0, &As[0][wid * 512]);
    gll16(gA1, &As[0][2048 + wid * 512]);
    gll16(gB0, &Bs[0][wid * 512]);
    gll16(gB1, &Bs[0][2048 + wid * 512]);

    int cur = 0;
    for (int t = 0; t < nt; ++t) {
        if (t + 1 < nt) {   // issue next tile's 4 loads; they stay in flight
            int kk = (t + 1) << 5;
            gll16(gA0 + kk, &As[cur ^ 1][wid * 512]);
            gll16(gA1 + kk, &As[cur ^ 1][2048 + wid * 512]);
            gll16(gB0 + kk, &Bs[cur ^ 1][wid * 512]);
            gll16(gB1 + kk, &Bs[cur ^ 1][2048 + wid * 512]);
            // wait only for tile t's 4 (oldest); next tile's 4 remain in flight
            asm volatile("s_waitcnt vmcnt(4)" ::: "memory");
        } else {
            asm volatile("s_waitcnt vmcnt(0)" ::: "memory");
        }
        __builtin_amdgcn_s_barrier();          // all waves: tile-t data in LDS
        __builtin_amdgcn_sched_barrier(0);     // pin: no ds_read hoisted above
        v8bf af[4], bfr[4];
#pragma unroll
        for (int i = 0; i < 4; ++i)
            af[i] = __builtin_bit_cast(v8bf, *(const v8u16*)&As[cur][(wm * 64 + i * 16 + l16) * 32 + quad * 8]);
#pragma unroll
        for (int i = 0; i < 4; ++i)
            bfr[i] = __builtin_bit_cast(v8bf, *(const v8u16*)&Bs[cur][(wn * 64 + i * 16 + l16) * 32 + quad * 8]);
#pragma unroll
        for (int mi = 0; mi < 4; ++mi)
#pragma unroll
            for (int ni = 0; ni < 4; ++ni)
                acc[mi][ni] = __builtin_amdgcn_mfma_f32_16x16x32_bf16(af[mi], bfr[ni], acc[mi][ni], 0, 0, 0);
        __builtin_amdgcn_s_barrier();          // WAR: all reads of buf[cur] done
        __builtin_amdgcn_sched_barrier(0);     // pin: next stage not hoisted above
        cur ^= 1;
    }

    float rs[4][4], rd[4][4];
#pragma unroll
    for (int mi = 0; mi < 4; ++mi)
#pragma unroll
        for (int rr = 0; rr < 4; ++rr) { rs[mi][rr] = 0.f; rd[mi][rr] = 0.f; }

#pragma unroll
    for (int mi = 0; mi < 4; ++mi)
#pragma unroll
        for (int ni = 0; ni < 4; ++ni) {
            int col = tileN + wn * 64 + ni * 16 + l16;
            float bb = bias ? bias[col] : 0.f;
            float ws_ = avs ? avs[col] : 0.f;
            float wd_ = avd ? avd[col] : 0.f;
            int row0 = tileM + wm * 64 + mi * 16 + quad * 4;
#pragma unroll
            for (int rr = 0; rr < 4; ++rr) {
                int row = row0 + rr;
                if (row < M) {
                    float v = acc[mi][ni][rr] + bb;
                    if (relu) v = fmaxf(v, 0.f);
                    if (outf32) ((float*)Cv)[(size_t)row * N + col] = v;
                    else        ((u16*)Cv)[(size_t)row * N + col] = f2b(v);
                    rs[mi][rr] += v * ws_;
                    rd[mi][rr] += v * wd_;
                }
            }
        }

    if (avs) {   // fused alpha: reduce 16 col-lanes per quad, one atomic per row
#pragma unroll
        for (int mi = 0; mi < 4; ++mi)
#pragma unroll
            for (int rr = 0; rr < 4; ++rr) {
                int row = tileM + wm * 64 + mi * 16 + quad * 4 + rr;
                float a = rs[mi][rr], b = rd[mi][rr];
                a += __shfl_down(a, 8, 64); a += __shfl_down(a, 4, 64);
                a += __shfl_down(a, 2, 64); a += __shfl_down(a, 1, 64);
                b += __shfl_down(b, 8, 64); b += __shfl_down(b, 4, 64);
                b += __shfl_down(b, 2, 64); b += __shfl_down(b, 1, 64);
                if (l16 == 0 && row < M) {
                    atomicAdd(&aout_s[row], a);
                    atomicAdd(&aout_d[row], b);
                }
            }
    }
}

// ---------------- launch ----------------

extern "C" void kernel_launch(void* const* d_in, const int* in_sizes, int n_in,
                              void* d_out, int out_size, void* d_ws, size_t ws_size,
                              hipStream_t stream) {
    const float* x  = (const float*)d_in[0];
    const int* ei1  = (const int*)d_in[1];
    const int* ei2  = (const int*)d_in[2];
    const float* W1s = (const float*)d_in[3];
    const float* W1d = (const float*)d_in[4];
    const float* a1s = (const float*)d_in[5];
    const float* a1d = (const float*)d_in[6];
    const float* b1  = (const float*)d_in[7];
    const float* Wl1 = (const float*)d_in[8];
    const float* bl1 = (const float*)d_in[9];
    const float* W2s = (const float*)d_in[10];
    const float* W2d = (const float*)d_in[11];
    const float* a2s = (const float*)d_in[12];
    const float* a2d = (const float*)d_in[13];
    const float* b2  = (const float*)d_in[14];
    const float* Wl2 = (const float*)d_in[15];
    const float* bl2 = (const float*)d_in[16];
    float* out = (float*)d_out;

    char* ws = (char*)d_ws;
    size_t off = 0;
    auto alloc = [&](size_t b) { void* p = ws + off; off = (off + b + 255) & ~(size_t)255; return p; };
    u16* bufA   = (u16*)alloc((size_t)NN * 512 * 2);   // Hsrc1 -> hmid
    u16* bufB   = (u16*)alloc((size_t)NN * 512 * 2);   // xb16 -> g1 -> Hsrc2(lo)+g2(hi)
    int* rp     = (int*)alloc((size_t)2 * (NN + 1) * 4);
    int* srcp   = (int*)alloc((size_t)2 * EE * 4);
    int* dstp   = (int*)alloc((size_t)2 * EE * 4);
    int* deg    = (int*)alloc((size_t)2 * NN * 4);
    int* bsum   = (int*)alloc((size_t)2 * NB_PER_SET * 4);
    float* ex   = (float*)alloc((size_t)2 * EE * 4);
    float* asrc = (float*)alloc((size_t)NN * 4);
    float* adst = (float*)alloc((size_t)NN * 4);
    float* vbuf = (float*)alloc(2048 * 4);             // v1s|v1d|v2s|v2d
    u16* Wt1s   = (u16*)alloc((size_t)512 * 512 * 2);
    u16* Wtl1   = (u16*)alloc((size_t)512 * 512 * 2);
    u16* Wt2s   = (u16*)alloc((size_t)512 * 256 * 2);
    u16* Wtl2   = (u16*)alloc((size_t)256 * 256 * 2);
    u16* g2buf  = bufB + (size_t)NN * 256;

    // CSR build (both sets)
    hipMemsetAsync(deg, 0, (size_t)2 * NN * 4, stream);
    deg2_kernel<<<(2 * EE + 255) / 256, 256, 0, stream>>>(ei1, ei2, deg);
    scan_partial<<<2 * NB_PER_SET, 256, 0, stream>>>(deg, bsum);
    scan_tops<<<1, 256, 0, stream>>>(bsum);
    scan_final<<<2 * NB_PER_SET, 256, 0, stream>>>(deg, bsum, rp);
    fill2_kernel<<<(2 * EE + 255) / 256, 256, 0, stream>>>(ei1, ei2, rp, deg, srcp, dstp);

    // weight prep
    transpose4<<<(720896 + 255) / 256, 256, 0, stream>>>(W1s, Wt1s, Wl1, Wtl1, W2s, Wt2s, Wl2, Wtl2);
    wv4<<<512, 256, 0, stream>>>(W1s, W1d, W2s, W2d, a1s, a1d, a2s, a2d, vbuf);

    // ---- layer 1 ----
    alpha_pair_f32x<<<(NN + 3) / 4, 256, 0, stream>>>(x, vbuf, vbuf + 512, asrc, adst, bufB, NN);
    edge_ex<<<(2 * EE + 255) / 256, 256, 0, stream>>>(srcp, dstp, asrc, adst, ex);
    gemm_bf16<<<dim3(4, 391), 256, 0, stream>>>(bufB, Wt1s, bufA, NN, 512, 512, nullptr, 0, 0,
                                                nullptr, nullptr, nullptr, nullptr);
    gat_pull<8><<<(NN + 3) / 4, 256, 0, stream>>>(rp, srcp, ex, bufA, b1, bufB, NN);
    // layer-2 alpha dots fused into gemm2 epilogue; zero the accumulators first
    hipMemsetAsync(asrc, 0, (size_t)NN * 4, stream);
    hipMemsetAsync(adst, 0, (size_t)NN * 4, stream);
    gemm_bf16<<<dim3(4, 391), 256, 0, stream>>>(bufB, Wtl1, bufA, NN, 512, 512, bl1, 1, 0,
                                                vbuf + 1024, vbuf + 1536, asrc, adst);

    // ---- layer 2 ----
    edge_ex<<<(2 * EE + 255) / 256, 256, 0, stream>>>(srcp, dstp, asrc, adst, ex);
    gemm_bf16<<<dim3(2, 391), 256, 0, stream>>>(bufA, Wt2s, bufB, NN, 256, 512, nullptr, 0, 0,
                                                nullptr, nullptr, nullptr, nullptr);
    gat_pull<4><<<(NN + 3) / 4, 256, 0, stream>>>(rp, srcp, ex, bufB, b2, g2buf, NN);
    gemm_bf16<<<dim3(2, 391), 256, 0, stream>>>(g2buf, Wtl2, out, NN, 256, 256, bl2, 0, 1,
                                                nullptr, nullptr, nullptr, nullptr);

    (void)in_sizes; (void)n_in; (void)out_size; (void)ws_size;
}

// Round 6
// 507.744 us; speedup vs baseline: 1.0333x; 1.0333x over previous
//
#include <hip/hip_runtime.h>

typedef unsigned short u16;
typedef __attribute__((ext_vector_type(8))) unsigned short v8u16;
typedef __attribute__((ext_vector_type(4))) unsigned short v4u16;
typedef __attribute__((ext_vector_type(8))) __bf16 v8bf;
typedef __attribute__((ext_vector_type(4))) float v4f;

#define NN 50000
#define EE 150000
#define SCAN_CHUNK 512
#define NB_PER_SET 98   // ceil(NN / SCAN_CHUNK)

__device__ inline float b2f(u16 u) {
    union { unsigned int i; float f; } x; x.i = ((unsigned int)u) << 16; return x.f;
}
__device__ inline u16 f2b(float f) {
    union { float f; unsigned int i; } x; x.f = f;
    unsigned int r = x.i + 0x7FFFu + ((x.i >> 16) & 1u);
    return (u16)(r >> 16);
}
__device__ inline float wred(float v) {
    v += __shfl_down(v, 32, 64);
    v += __shfl_down(v, 16, 64);
    v += __shfl_down(v, 8, 64);
    v += __shfl_down(v, 4, 64);
    v += __shfl_down(v, 2, 64);
    v += __shfl_down(v, 1, 64);
    return v;
}
__device__ inline int wred_i(int v) {
    v += __shfl_down(v, 32, 64);
    v += __shfl_down(v, 16, 64);
    v += __shfl_down(v, 8, 64);
    v += __shfl_down(v, 4, 64);
    v += __shfl_down(v, 2, 64);
    v += __shfl_down(v, 1, 64);
    return v;
}

// async global->LDS, 16B per lane; LDS dest is wave-uniform base + lane*16
__device__ __forceinline__ void gll16(const u16* g, u16* l) {
    __builtin_amdgcn_global_load_lds(
        (const __attribute__((address_space(1))) void*)g,
        (__attribute__((address_space(3))) void*)l, 16, 0, 0);
}

// ---------------- fused weight prep ----------------

__global__ void transpose4(const float* __restrict__ W0, u16* __restrict__ T0,
                           const float* __restrict__ W1, u16* __restrict__ T1,
                           const float* __restrict__ W2, u16* __restrict__ T2,
                           const float* __restrict__ W3, u16* __restrict__ T3) {
    int idx = blockIdx.x * blockDim.x + threadIdx.x;
    const float* W; u16* T; int N, K, base;
    if (idx < 262144)      { W = W0; T = T0; K = 512; N = 512; base = 0; }
    else if (idx < 524288) { W = W1; T = T1; K = 512; N = 512; base = 262144; }
    else if (idx < 655360) { W = W2; T = T2; K = 512; N = 256; base = 524288; }
    else if (idx < 720896) { W = W3; T = T3; K = 256; N = 256; base = 655360; }
    else return;
    int i = idx - base;
    int n = i % N, k = i / N;
    T[(size_t)n * K + k] = f2b(W[i]);
}

__global__ void wv4(const float* __restrict__ Wa, const float* __restrict__ Wb,
                    const float* __restrict__ Wc, const float* __restrict__ Wd,
                    const float* __restrict__ aa, const float* __restrict__ ab,
                    const float* __restrict__ ac, const float* __restrict__ ad,
                    float* __restrict__ vbuf) {
    int rw = (blockIdx.x * blockDim.x + threadIdx.x) >> 6;  // 0..2047
    int lane = threadIdx.x & 63;
    if (rw >= 2048) return;
    int seg = rw >> 9, r = rw & 511;
    const float* W; const float* a; int C;
    if (seg == 0)      { W = Wa; a = aa; C = 512; }
    else if (seg == 1) { W = Wb; a = ab; C = 512; }
    else if (seg == 2) { W = Wc; a = ac; C = 256; }
    else               { W = Wd; a = ad; C = 256; }
    float s = 0.f;
    int c0 = lane * 8;
    if (c0 < C) {
        const float* wp = W + (size_t)r * C + c0;
        v4f w0 = *(const v4f*)wp;
        v4f w1 = *(const v4f*)(wp + 4);
        v4f a0 = *(const v4f*)(a + c0);
        v4f a1 = *(const v4f*)(a + c0 + 4);
#pragma unroll
        for (int j = 0; j < 4; ++j) s += w0[j] * a0[j] + w1[j] * a1[j];
    }
    s = wred(s);
    if (lane == 0) vbuf[rw] = s;
}

// asrc/adst GEMV pair + bf16 downcast of x (one wave per node, D=512)
__global__ void alpha_pair_f32x(const float* __restrict__ X, const float* __restrict__ vs,
                                const float* __restrict__ vd, float* __restrict__ as_,
                                float* __restrict__ ad_, u16* __restrict__ Xb, int Nn) {
    int w = (blockIdx.x * blockDim.x + threadIdx.x) >> 6;
    int lane = threadIdx.x & 63;
    if (w >= Nn) return;
    const float* xp = X + (size_t)w * 512 + lane * 8;
    v4f x0 = *(const v4f*)xp;
    v4f x1 = *(const v4f*)(xp + 4);
    const float* vsp = vs + lane * 8;
    const float* vdp = vd + lane * 8;
    float s1 = 0.f, s2 = 0.f;
    v8u16 o;
#pragma unroll
    for (int j = 0; j < 4; ++j) {
        s1 += x0[j] * vsp[j] + x1[j] * vsp[j + 4];
        s2 += x0[j] * vdp[j] + x1[j] * vdp[j + 4];
        o[j] = f2b(x0[j]); o[j + 4] = f2b(x1[j]);
    }
    *(v8u16*)(Xb + (size_t)w * 512 + lane * 8) = o;
    s1 = wred(s1);
    s2 = wred(s2);
    if (lane == 0) { as_[w] = s1; ad_[w] = s2; }
}

// ---------------- CSR build, both edge sets fused ----------------

__global__ void deg2_kernel(const int* __restrict__ ei1, const int* __restrict__ ei2,
                            int* __restrict__ deg) {
    int idx = blockIdx.x * blockDim.x + threadIdx.x;
    if (idx >= 2 * EE) return;
    int set = idx >= EE;
    int e = idx - set * EE;
    const int* ei = set ? ei2 : ei1;
    atomicAdd(&deg[set * NN + ei[EE + e]], 1);
}

// multi-block exclusive scan of deg (2 independent segments of NN) -> rp
// pass 1: per-block (512-elem chunk) sums
__global__ void scan_partial(const int* __restrict__ deg, int* __restrict__ bsum) {
    int b = blockIdx.x;                       // 0..2*NB_PER_SET-1
    int set = b / NB_PER_SET, lb = b - set * NB_PER_SET;
    int tid = threadIdx.x;                    // 256
    int i0 = lb * SCAN_CHUNK + tid * 2;
    int s = 0;
    if (i0 < NN)     s += deg[set * NN + i0];
    if (i0 + 1 < NN) s += deg[set * NN + i0 + 1];
    s = wred_i(s);
    __shared__ int lsum[4];
    if ((tid & 63) == 0) lsum[tid >> 6] = s;
    __syncthreads();
    if (tid == 0) bsum[b] = lsum[0] + lsum[1] + lsum[2] + lsum[3];
}

// pass 2: one block; exclusive scan of the 98 block sums within each set
__global__ void scan_tops(int* __restrict__ bsum) {
    __shared__ int ls[256];
    int tid = threadIdx.x;                    // 256 = 2 sets x 128 slots
    int set = tid >> 7, lb = tid & 127;
    int v = (lb < NB_PER_SET) ? bsum[set * NB_PER_SET + lb] : 0;
    ls[tid] = v;
    __syncthreads();
    for (int off = 1; off < 128; off <<= 1) {
        int t = (lb >= off) ? ls[tid - off] : 0;
        __syncthreads();
        ls[tid] += t;
        __syncthreads();
    }
    if (lb < NB_PER_SET) bsum[set * NB_PER_SET + lb] = ls[tid] - v;  // exclusive
}

// pass 3: per-block local exclusive scan + block offset -> rp
__global__ void scan_final(const int* __restrict__ deg, const int* __restrict__ bsum,
                           int* __restrict__ rp) {
    int b = blockIdx.x;
    int set = b / NB_PER_SET, lb = b - set * NB_PER_SET;
    int tid = threadIdx.x;                    // 256
    int i0 = lb * SCAN_CHUNK + tid * 2;
    int d0 = (i0 < NN)     ? deg[set * NN + i0]     : 0;
    int d1 = (i0 + 1 < NN) ? deg[set * NN + i0 + 1] : 0;
    int pair = d0 + d1;
    __shared__ int ps[256];
    ps[tid] = pair;
    __syncthreads();
    for (int off = 1; off < 256; off <<= 1) {
        int t = (tid >= off) ? ps[tid - off] : 0;
        __syncthreads();
        ps[tid] += t;
        __syncthreads();
    }
    int base = bsum[b] + ps[tid] - pair;      // exclusive over this block's pairs
    if (i0 < NN)     rp[set * (NN + 1) + i0] = base;
    if (i0 + 1 < NN) rp[set * (NN + 1) + i0 + 1] = base + d0;
    if (b == 0 && tid == 0) { rp[NN] = EE; rp[(NN + 1) + NN] = EE; }
}

// fill permuted edge arrays; consumes deg via atomicSub (no cursor/memset needed)
__global__ void fill2_kernel(const int* __restrict__ ei1, const int* __restrict__ ei2,
                             const int* __restrict__ rp, int* __restrict__ deg,
                             int* __restrict__ srcp, int* __restrict__ dstp) {
    int idx = blockIdx.x * blockDim.x + threadIdx.x;
    if (idx >= 2 * EE) return;
    int set = idx >= EE;
    int e = idx - set * EE;
    const int* ei = set ? ei2 : ei1;
    int d = ei[EE + e];
    int old = atomicSub(&deg[set * NN + d], 1);
    int pos = rp[set * (NN + 1) + d] + old - 1;
    srcp[set * EE + pos] = ei[e];
    dstp[set * EE + pos] = d;
}

// per-layer edge weights: ex[i] = exp(leaky(asrc[src]+adst[dst])), both sets
__global__ void edge_ex(const int* __restrict__ srcp, const int* __restrict__ dstp,
                        const float* __restrict__ asrc, const float* __restrict__ adst,
                        float* __restrict__ ex) {
    int i = blockIdx.x * blockDim.x + threadIdx.x;
    if (i >= 2 * EE) return;
    float t = asrc[srcp[i]] + adst[dstp[i]];
    t = t > 0.f ? t : 0.2f * t;
    ex[i] = __expf(fminf(t, 60.f));
}

// ---------------- pull aggregate: one wave per dst node ----------------
// Software-pipelined: next edge's (w,s) and H-row load issued BEFORE consuming
// the current H-row (G7: break the serial dependent-load chain; span -> L/2).
template <int CV>
__global__ void gat_pull(const int* __restrict__ rp, const int* __restrict__ srcp,
                         const float* __restrict__ ex, const u16* __restrict__ H,
                         const float* __restrict__ bias, u16* __restrict__ G, int Nn) {
    const int C = CV * 64;
    int d = (blockIdx.x * blockDim.x + threadIdx.x) >> 6;
    int lane = threadIdx.x & 63;
    if (d >= Nn) return;
    float out[CV];
#pragma unroll
    for (int j = 0; j < CV; ++j) out[j] = 0.f;
#pragma unroll
    for (int set = 0; set < 2; ++set) {
        const int* rpS = rp + set * (NN + 1);
        int base = set * EE;
        int beg = rpS[d], end = rpS[d + 1];
        float acc[CV];
#pragma unroll
        for (int j = 0; j < CV; ++j) acc[j] = 0.f;
        float ssum = 0.f;
        if (beg < end) {
            float w0 = ex[base + beg];
            int s0 = srcp[base + beg];
            if constexpr (CV == 8) {
                v8u16 h0 = *(const v8u16*)(H + (size_t)s0 * C + lane * 8);
                for (int i = beg + 1; i < end; ++i) {
                    float w1 = ex[base + i];
                    int s1 = srcp[base + i];
                    v8u16 h1 = *(const v8u16*)(H + (size_t)s1 * C + lane * 8);
                    ssum += w0;
#pragma unroll
                    for (int j = 0; j < 8; ++j) acc[j] += w0 * b2f(h0[j]);
                    w0 = w1; h0 = h1;
                }
                ssum += w0;
#pragma unroll
                for (int j = 0; j < 8; ++j) acc[j] += w0 * b2f(h0[j]);
            } else {
                v4u16 h0 = *(const v4u16*)(H + (size_t)s0 * C + lane * 4);
                for (int i = beg + 1; i < end; ++i) {
                    float w1 = ex[base + i];
                    int s1 = srcp[base + i];
                    v4u16 h1 = *(const v4u16*)(H + (size_t)s1 * C + lane * 4);
                    ssum += w0;
#pragma unroll
                    for (int j = 0; j < 4; ++j) acc[j] += w0 * b2f(h0[j]);
                    w0 = w1; h0 = h1;
                }
                ssum += w0;
#pragma unroll
                for (int j = 0; j < 4; ++j) acc[j] += w0 * b2f(h0[j]);
            }
        }
        float inv = 1.f / (ssum + 1e-16f);
#pragma unroll
        for (int j = 0; j < CV; ++j) out[j] += acc[j] * inv;
    }
    const float* bp = bias + lane * CV;
    u16* gp = G + (size_t)d * C + lane * CV;
    if constexpr (CV == 8) {
        v8u16 o;
#pragma unroll
        for (int j = 0; j < 8; ++j) o[j] = f2b(out[j] + 2.f * bp[j]);
        *(v8u16*)gp = o;
    } else {
        v4u16 o;
#pragma unroll
        for (int j = 0; j < 4; ++j) o[j] = f2b(out[j] + 2.f * bp[j]);
        *(v4u16*)gp = o;
    }
}

// ---------------- MFMA GEMM: measured-best structure (round-2): 128x128 tile,
// BK=32, SINGLE-buffered, 2x __syncthreads per K-step, linear LDS,
// global_load_lds width=16; + bijective chunked XCD swizzle (FETCH 101->29.6MB)
// + optional fused per-row alpha dots in the epilogue.
// C[M,N] = A[M,K] @ Bt[N,K]^T. bf16 in, fp32 accum; out bf16 or fp32; bias/relu.
__global__ __launch_bounds__(256, 2) void gemm_bf16(
    const u16* __restrict__ A, const u16* __restrict__ Bt, void* __restrict__ Cv,
    int M, int N, int K, const float* __restrict__ bias, int relu, int outf32,
    const float* __restrict__ avs, const float* __restrict__ avd,
    float* __restrict__ aout_s, float* __restrict__ aout_d) {
    __shared__ u16 As[128 * 32];   // linear [row][32], 8 KB
    __shared__ u16 Bs[128 * 32];
    const int tid = threadIdx.x;
    const int lane = tid & 63;
    const int wid = tid >> 6;
    const int wm = wid >> 1;
    const int wn = wid & 1;
    const int quad = lane >> 4;
    const int l16 = lane & 15;

    // bijective chunked XCD swizzle
    const int nwg = gridDim.x * gridDim.y;
    const int orig = blockIdx.y * gridDim.x + blockIdx.x;
    const int q = nwg >> 3, r = nwg & 7;
    const int xcd = orig & 7, loc = orig >> 3;
    const int wg = (xcd < r ? xcd * (q + 1) : r * (q + 1) + (xcd - r) * q) + loc;
    const int tileM = (wg / gridDim.x) * 128;
    const int tileN = (wg % gridDim.x) * 128;

    // staging: thread t loads 16B at (row = t>>2, col = (t&3)*8); LDS linear in t
    const int srow = tid >> 2;
    const int scol = (tid & 3) * 8;
    int ra0 = tileM + srow;       if (ra0 >= M) ra0 = M - 1;
    int ra1 = tileM + 64 + srow;  if (ra1 >= M) ra1 = M - 1;
    const u16* gA0 = A + (size_t)ra0 * K + scol;
    const u16* gA1 = A + (size_t)ra1 * K + scol;
    const u16* gB0 = Bt + (size_t)(tileN + srow) * K + scol;
    const u16* gB1 = Bt + (size_t)(tileN + 64 + srow) * K + scol;
    u16* lA0 = As + wid * 512;          // wave-uniform LDS bases (u16 units)
    u16* lA1 = As + 2048 + wid * 512;
    u16* lB0 = Bs + wid * 512;
    u16* lB1 = Bs + 2048 + wid * 512;

    v4f acc[4][4];
#pragma unroll
    for (int i = 0; i < 4; ++i)
#pragma unroll
        for (int j = 0; j < 4; ++j) acc[i][j] = v4f{0.f, 0.f, 0.f, 0.f};

    for (int k0 = 0; k0 < K; k0 += 32) {
        gll16(gA0 + k0, lA0);
        gll16(gA1 + k0, lA1);
        gll16(gB0 + k0, lB0);
        gll16(gB1 + k0, lB1);
        __syncthreads();
        v8bf af[4], bfr[4];
#pragma unroll
        for (int i = 0; i < 4; ++i)
            af[i] = __builtin_bit_cast(v8bf, *(const v8u16*)&As[(wm * 64 + i * 16 + l16) * 32 + quad * 8]);
#pragma unroll
        for (int i = 0; i < 4; ++i)
            bfr[i] = __builtin_bit_cast(v8bf, *(const v8u16*)&Bs[(wn * 64 + i * 16 + l16) * 32 + quad * 8]);
#pragma unroll
        for (int mi = 0; mi < 4; ++mi)
#pragma unroll
            for (int ni = 0; ni < 4; ++ni)
                acc[mi][ni] = __builtin_amdgcn_mfma_f32_16x16x32_bf16(af[mi], bfr[ni], acc[mi][ni], 0, 0, 0);
        __syncthreads();
    }

    float rs[4][4], rd[4][4];
#pragma unroll
    for (int mi = 0; mi < 4; ++mi)
#pragma unroll
        for (int rr = 0; rr < 4; ++rr) { rs[mi][rr] = 0.f; rd[mi][rr] = 0.f; }

#pragma unroll
    for (int mi = 0; mi < 4; ++mi)
#pragma unroll
        for (int ni = 0; ni < 4; ++ni) {
            int col = tileN + wn * 64 + ni * 16 + l16;
            float bb = bias ? bias[col] : 0.f;
            float ws_ = avs ? avs[col] : 0.f;
            float wd_ = avd ? avd[col] : 0.f;
            int row0 = tileM + wm * 64 + mi * 16 + quad * 4;
#pragma unroll
            for (int rr = 0; rr < 4; ++rr) {
                int row = row0 + rr;
                if (row < M) {
                    float v = acc[mi][ni][rr] + bb;
                    if (relu) v = fmaxf(v, 0.f);
                    if (outf32) ((float*)Cv)[(size_t)row * N + col] = v;
                    else        ((u16*)Cv)[(size_t)row * N + col] = f2b(v);
                    rs[mi][rr] += v * ws_;
                    rd[mi][rr] += v * wd_;
                }
            }
        }

    if (avs) {   // fused alpha: reduce 16 col-lanes per quad, one atomic per row
#pragma unroll
        for (int mi = 0; mi < 4; ++mi)
#pragma unroll
            for (int rr = 0; rr < 4; ++rr) {
                int row = tileM + wm * 64 + mi * 16 + quad * 4 + rr;
                float a = rs[mi][rr], b = rd[mi][rr];
                a += __shfl_down(a, 8, 64); a += __shfl_down(a, 4, 64);
                a += __shfl_down(a, 2, 64); a += __shfl_down(a, 1, 64);
                b += __shfl_down(b, 8, 64); b += __shfl_down(b, 4, 64);
                b += __shfl_down(b, 2, 64); b += __shfl_down(b, 1, 64);
                if (l16 == 0 && row < M) {
                    atomicAdd(&aout_s[row], a);
                    atomicAdd(&aout_d[row], b);
                }
            }
    }
}

// ---------------- launch ----------------

extern "C" void kernel_launch(void* const* d_in, const int* in_sizes, int n_in,
                              void* d_out, int out_size, void* d_ws, size_t ws_size,
                              hipStream_t stream) {
    const float* x  = (const float*)d_in[0];
    const int* ei1  = (const int*)d_in[1];
    const int* ei2  = (const int*)d_in[2];
    const float* W1s = (const float*)d_in[3];
    const float* W1d = (const float*)d_in[4];
    const float* a1s = (const float*)d_in[5];
    const float* a1d = (const float*)d_in[6];
    const float* b1  = (const float*)d_in[7];
    const float* Wl1 = (const float*)d_in[8];
    const float* bl1 = (const float*)d_in[9];
    const float* W2s = (const float*)d_in[10];
    const float* W2d = (const float*)d_in[11];
    const float* a2s = (const float*)d_in[12];
    const float* a2d = (const float*)d_in[13];
    const float* b2  = (const float*)d_in[14];
    const float* Wl2 = (const float*)d_in[15];
    const float* bl2 = (const float*)d_in[16];
    float* out = (float*)d_out;

    char* ws = (char*)d_ws;
    size_t off = 0;
    auto alloc = [&](size_t b) { void* p = ws + off; off = (off + b + 255) & ~(size_t)255; return p; };
    u16* bufA   = (u16*)alloc((size_t)NN * 512 * 2);   // Hsrc1 -> hmid
    u16* bufB   = (u16*)alloc((size_t)NN * 512 * 2);   // xb16 -> g1 -> Hsrc2(lo)+g2(hi)
    int* rp     = (int*)alloc((size_t)2 * (NN + 1) * 4);
    int* srcp   = (int*)alloc((size_t)2 * EE * 4);
    int* dstp   = (int*)alloc((size_t)2 * EE * 4);
    int* deg    = (int*)alloc((size_t)2 * NN * 4);
    int* bsum   = (int*)alloc((size_t)2 * NB_PER_SET * 4);
    float* ex   = (float*)alloc((size_t)2 * EE * 4);
    float* asrc = (float*)alloc((size_t)NN * 4);
    float* adst = (float*)alloc((size_t)NN * 4);
    float* vbuf = (float*)alloc(2048 * 4);             // v1s|v1d|v2s|v2d
    u16* Wt1s   = (u16*)alloc((size_t)512 * 512 * 2);
    u16* Wtl1   = (u16*)alloc((size_t)512 * 512 * 2);
    u16* Wt2s   = (u16*)alloc((size_t)512 * 256 * 2);
    u16* Wtl2   = (u16*)alloc((size_t)256 * 256 * 2);
    u16* g2buf  = bufB + (size_t)NN * 256;

    // CSR build (both sets)
    hipMemsetAsync(deg, 0, (size_t)2 * NN * 4, stream);
    deg2_kernel<<<(2 * EE + 255) / 256, 256, 0, stream>>>(ei1, ei2, deg);
    scan_partial<<<2 * NB_PER_SET, 256, 0, stream>>>(deg, bsum);
    scan_tops<<<1, 256, 0, stream>>>(bsum);
    scan_final<<<2 * NB_PER_SET, 256, 0, stream>>>(deg, bsum, rp);
    fill2_kernel<<<(2 * EE + 255) / 256, 256, 0, stream>>>(ei1, ei2, rp, deg, srcp, dstp);

    // weight prep
    transpose4<<<(720896 + 255) / 256, 256, 0, stream>>>(W1s, Wt1s, Wl1, Wtl1, W2s, Wt2s, Wl2, Wtl2);
    wv4<<<512, 256, 0, stream>>>(W1s, W1d, W2s, W2d, a1s, a1d, a2s, a2d, vbuf);

    // ---- layer 1 ----
    alpha_pair_f32x<<<(NN + 3) / 4, 256, 0, stream>>>(x, vbuf, vbuf + 512, asrc, adst, bufB, NN);
    edge_ex<<<(2 * EE + 255) / 256, 256, 0, stream>>>(srcp, dstp, asrc, adst, ex);
    gemm_bf16<<<dim3(4, 391), 256, 0, stream>>>(bufB, Wt1s, bufA, NN, 512, 512, nullptr, 0, 0,
                                                nullptr, nullptr, nullptr, nullptr);
    gat_pull<8><<<(NN + 3) / 4, 256, 0, stream>>>(rp, srcp, ex, bufA, b1, bufB, NN);
    // layer-2 alpha dots fused into gemm2 epilogue; zero the accumulators first
    hipMemsetAsync(asrc, 0, (size_t)NN * 4, stream);
    hipMemsetAsync(adst, 0, (size_t)NN * 4, stream);
    gemm_bf16<<<dim3(4, 391), 256, 0, stream>>>(bufB, Wtl1, bufA, NN, 512, 512, bl1, 1, 0,
                                                vbuf + 1024, vbuf + 1536, asrc, adst);

    // ---- layer 2 ----
    edge_ex<<<(2 * EE + 255) / 256, 256, 0, stream>>>(srcp, dstp, asrc, adst, ex);
    gemm_bf16<<<dim3(2, 391), 256, 0, stream>>>(bufA, Wt2s, bufB, NN, 256, 512, nullptr, 0, 0,
                                                nullptr, nullptr, nullptr, nullptr);
    gat_pull<4><<<(NN + 3) / 4, 256, 0, stream>>>(rp, srcp, ex, bufB, b2, g2buf, NN);
    gemm_bf16<<<dim3(2, 391), 256, 0, stream>>>(g2buf, Wtl2, out, NN, 256, 256, bl2, 0, 1,
                                                nullptr, nullptr, nullptr, nullptr);

    (void)in_sizes; (void)n_in; (void)out_size; (void)ws_size;
}

// Round 7
// 506.835 us; speedup vs baseline: 1.0351x; 1.0018x over previous
//
#include <hip/hip_runtime.h>

typedef unsigned short u16;
typedef __attribute__((ext_vector_type(8))) unsigned short v8u16;
typedef __attribute__((ext_vector_type(4))) unsigned short v4u16;
typedef __attribute__((ext_vector_type(8))) __bf16 v8bf;
typedef __attribute__((ext_vector_type(4))) float v4f;

#define NN 50000
#define EE 150000
#define SCAN_CHUNK 512
#define NB_PER_SET 98   // ceil(NN / SCAN_CHUNK)

__device__ inline float b2f(u16 u) {
    union { unsigned int i; float f; } x; x.i = ((unsigned int)u) << 16; return x.f;
}
__device__ inline u16 f2b(float f) {
    union { float f; unsigned int i; } x; x.f = f;
    unsigned int r = x.i + 0x7FFFu + ((x.i >> 16) & 1u);
    return (u16)(r >> 16);
}
__device__ inline float wred(float v) {
    v += __shfl_down(v, 32, 64);
    v += __shfl_down(v, 16, 64);
    v += __shfl_down(v, 8, 64);
    v += __shfl_down(v, 4, 64);
    v += __shfl_down(v, 2, 64);
    v += __shfl_down(v, 1, 64);
    return v;
}
__device__ inline int wred_i(int v) {
    v += __shfl_down(v, 32, 64);
    v += __shfl_down(v, 16, 64);
    v += __shfl_down(v, 8, 64);
    v += __shfl_down(v, 4, 64);
    v += __shfl_down(v, 2, 64);
    v += __shfl_down(v, 1, 64);
    return v;
}

// async global->LDS, 16B per lane; LDS dest is wave-uniform base + lane*16
__device__ __forceinline__ void gll16(const u16* g, u16* l) {
    __builtin_amdgcn_global_load_lds(
        (const __attribute__((address_space(1))) void*)g,
        (__attribute__((address_space(3))) void*)l, 16, 0, 0);
}

// ---------------- weight prep ----------------

// LDS-tiled transpose + f32->bf16: coalesced reads AND writes (old version did
// 2B stride-K scattered stores). Input W[K][N] row-major, output T[N][K].
__global__ void transpose4t(const float* __restrict__ W0, u16* __restrict__ T0,
                            const float* __restrict__ W1, u16* __restrict__ T1,
                            const float* __restrict__ W2, u16* __restrict__ T2,
                            const float* __restrict__ W3, u16* __restrict__ T3) {
    int b = blockIdx.x;
    const float* W; u16* T; int N, K, t;
    if (b < 256)      { W = W0; T = T0; K = 512; N = 512; t = b; }
    else if (b < 512) { W = W1; T = T1; K = 512; N = 512; t = b - 256; }
    else if (b < 640) { W = W2; T = T2; K = 512; N = 256; t = b - 512; }
    else              { W = W3; T = T3; K = 256; N = 256; t = b - 640; }
    const int tilesN = N >> 5;
    const int kb = (t / tilesN) << 5;
    const int nb = (t % tilesN) << 5;
    __shared__ u16 tile[32][33];
    const int c = threadIdx.x & 31;
    const int r0 = threadIdx.x >> 5;   // 0..7
#pragma unroll
    for (int rr = 0; rr < 4; ++rr) {
        int r = r0 + rr * 8;
        tile[r][c] = f2b(W[(size_t)(kb + r) * N + nb + c]);
    }
    __syncthreads();
#pragma unroll
    for (int rr = 0; rr < 4; ++rr) {
        int r = r0 + rr * 8;
        T[(size_t)(nb + r) * K + kb + c] = tile[c][r];
    }
}

__global__ void wv4(const float* __restrict__ Wa, const float* __restrict__ Wb,
                    const float* __restrict__ Wc, const float* __restrict__ Wd,
                    const float* __restrict__ aa, const float* __restrict__ ab,
                    const float* __restrict__ ac, const float* __restrict__ ad,
                    float* __restrict__ vbuf) {
    int rw = (blockIdx.x * blockDim.x + threadIdx.x) >> 6;  // 0..2047
    int lane = threadIdx.x & 63;
    if (rw >= 2048) return;
    int seg = rw >> 9, r = rw & 511;
    const float* W; const float* a; int C;
    if (seg == 0)      { W = Wa; a = aa; C = 512; }
    else if (seg == 1) { W = Wb; a = ab; C = 512; }
    else if (seg == 2) { W = Wc; a = ac; C = 256; }
    else               { W = Wd; a = ad; C = 256; }
    float s = 0.f;
    int c0 = lane * 8;
    if (c0 < C) {
        const float* wp = W + (size_t)r * C + c0;
        v4f w0 = *(const v4f*)wp;
        v4f w1 = *(const v4f*)(wp + 4);
        v4f a0 = *(const v4f*)(a + c0);
        v4f a1 = *(const v4f*)(a + c0 + 4);
#pragma unroll
        for (int j = 0; j < 4; ++j) s += w0[j] * a0[j] + w1[j] * a1[j];
    }
    s = wred(s);
    if (lane == 0) vbuf[rw] = s;
}

// asrc/adst GEMV pair + bf16 downcast of x (one wave per node, D=512)
__global__ void alpha_pair_f32x(const float* __restrict__ X, const float* __restrict__ vs,
                                const float* __restrict__ vd, float* __restrict__ as_,
                                float* __restrict__ ad_, u16* __restrict__ Xb, int Nn) {
    int w = (blockIdx.x * blockDim.x + threadIdx.x) >> 6;
    int lane = threadIdx.x & 63;
    if (w >= Nn) return;
    const float* xp = X + (size_t)w * 512 + lane * 8;
    v4f x0 = *(const v4f*)xp;
    v4f x1 = *(const v4f*)(xp + 4);
    const float* vsp = vs + lane * 8;
    const float* vdp = vd + lane * 8;
    float s1 = 0.f, s2 = 0.f;
    v8u16 o;
#pragma unroll
    for (int j = 0; j < 4; ++j) {
        s1 += x0[j] * vsp[j] + x1[j] * vsp[j + 4];
        s2 += x0[j] * vdp[j] + x1[j] * vdp[j + 4];
        o[j] = f2b(x0[j]); o[j + 4] = f2b(x1[j]);
    }
    *(v8u16*)(Xb + (size_t)w * 512 + lane * 8) = o;
    s1 = wred(s1);
    s2 = wred(s2);
    if (lane == 0) { as_[w] = s1; ad_[w] = s2; }
}

// ---------------- CSR build, both edge sets fused ----------------

__global__ void deg2_kernel(const int* __restrict__ ei1, const int* __restrict__ ei2,
                            int* __restrict__ deg) {
    int idx = blockIdx.x * blockDim.x + threadIdx.x;
    if (idx >= 2 * EE) return;
    int set = idx >= EE;
    int e = idx - set * EE;
    const int* ei = set ? ei2 : ei1;
    atomicAdd(&deg[set * NN + ei[EE + e]], 1);
}

// multi-block exclusive scan of deg (2 independent segments of NN) -> rp
__global__ void scan_partial(const int* __restrict__ deg, int* __restrict__ bsum) {
    int b = blockIdx.x;                       // 0..2*NB_PER_SET-1
    int set = b / NB_PER_SET, lb = b - set * NB_PER_SET;
    int tid = threadIdx.x;                    // 256
    int i0 = lb * SCAN_CHUNK + tid * 2;
    int s = 0;
    if (i0 < NN)     s += deg[set * NN + i0];
    if (i0 + 1 < NN) s += deg[set * NN + i0 + 1];
    s = wred_i(s);
    __shared__ int lsum[4];
    if ((tid & 63) == 0) lsum[tid >> 6] = s;
    __syncthreads();
    if (tid == 0) bsum[b] = lsum[0] + lsum[1] + lsum[2] + lsum[3];
}

__global__ void scan_tops(int* __restrict__ bsum) {
    __shared__ int ls[256];
    int tid = threadIdx.x;                    // 256 = 2 sets x 128 slots
    int set = tid >> 7, lb = tid & 127;
    int v = (lb < NB_PER_SET) ? bsum[set * NB_PER_SET + lb] : 0;
    ls[tid] = v;
    __syncthreads();
    for (int off = 1; off < 128; off <<= 1) {
        int t = (lb >= off) ? ls[tid - off] : 0;
        __syncthreads();
        ls[tid] += t;
        __syncthreads();
    }
    if (lb < NB_PER_SET) bsum[set * NB_PER_SET + lb] = ls[tid] - v;  // exclusive
}

__global__ void scan_final(const int* __restrict__ deg, const int* __restrict__ bsum,
                           int* __restrict__ rp) {
    int b = blockIdx.x;
    int set = b / NB_PER_SET, lb = b - set * NB_PER_SET;
    int tid = threadIdx.x;                    // 256
    int i0 = lb * SCAN_CHUNK + tid * 2;
    int d0 = (i0 < NN)     ? deg[set * NN + i0]     : 0;
    int d1 = (i0 + 1 < NN) ? deg[set * NN + i0 + 1] : 0;
    int pair = d0 + d1;
    __shared__ int ps[256];
    ps[tid] = pair;
    __syncthreads();
    for (int off = 1; off < 256; off <<= 1) {
        int t = (tid >= off) ? ps[tid - off] : 0;
        __syncthreads();
        ps[tid] += t;
        __syncthreads();
    }
    int base = bsum[b] + ps[tid] - pair;      // exclusive over this block's pairs
    if (i0 < NN)     rp[set * (NN + 1) + i0] = base;
    if (i0 + 1 < NN) rp[set * (NN + 1) + i0 + 1] = base + d0;
    if (b == 0 && tid == 0) { rp[NN] = EE; rp[(NN + 1) + NN] = EE; }
}

__global__ void fill2_kernel(const int* __restrict__ ei1, const int* __restrict__ ei2,
                             const int* __restrict__ rp, int* __restrict__ deg,
                             int* __restrict__ srcp, int* __restrict__ dstp) {
    int idx = blockIdx.x * blockDim.x + threadIdx.x;
    if (idx >= 2 * EE) return;
    int set = idx >= EE;
    int e = idx - set * EE;
    const int* ei = set ? ei2 : ei1;
    int d = ei[EE + e];
    int old = atomicSub(&deg[set * NN + d], 1);
    int pos = rp[set * (NN + 1) + d] + old - 1;
    srcp[set * EE + pos] = ei[e];
    dstp[set * EE + pos] = d;
}

// per-layer edge weights: ex[i] = exp(leaky(asrc[src]+adst[dst])), both sets
__global__ void edge_ex(const int* __restrict__ srcp, const int* __restrict__ dstp,
                        const float* __restrict__ asrc, const float* __restrict__ adst,
                        float* __restrict__ ex) {
    int i = blockIdx.x * blockDim.x + threadIdx.x;
    if (i >= 2 * EE) return;
    float t = asrc[srcp[i]] + adst[dstp[i]];
    t = t > 0.f ? t : 0.2f * t;
    ex[i] = __expf(fminf(t, 60.f));
}

// ---------------- pull aggregate: one wave per dst node ----------------
// 2-deep software pipeline on the dependent-load chain (G7): exposure -> L/3.
// Optionally zeroes z1/z2 (piggyback, replaces two memset launches).
template <int CV>
__global__ void gat_pull(const int* __restrict__ rp, const int* __restrict__ srcp,
                         const float* __restrict__ ex, const u16* __restrict__ H,
                         const float* __restrict__ bias, u16* __restrict__ G, int Nn,
                         float* __restrict__ z1, float* __restrict__ z2) {
    const int C = CV * 64;
    int gid = blockIdx.x * blockDim.x + threadIdx.x;
    if (z1 && gid < NN) { z1[gid] = 0.f; z2[gid] = 0.f; }
    int d = gid >> 6;
    int lane = threadIdx.x & 63;
    if (d >= Nn) return;
    float out[CV];
#pragma unroll
    for (int j = 0; j < CV; ++j) out[j] = 0.f;
#pragma unroll
    for (int set = 0; set < 2; ++set) {
        const int* rpS = rp + set * (NN + 1);
        int base = set * EE;
        int beg = rpS[d], end = rpS[d + 1];
        float acc[CV];
#pragma unroll
        for (int j = 0; j < CV; ++j) acc[j] = 0.f;
        float ssum = 0.f;
        int n = end - beg;
        if (n > 0) {
            const float* exS = ex + base;
            const int* srcS = srcp + base;
            if constexpr (CV == 8) {
                float w0 = exS[beg];
                v8u16 h0 = *(const v8u16*)(H + (size_t)srcS[beg] * C + lane * 8);
                float w1 = 0.f; v8u16 h1{};
                if (n > 1) { w1 = exS[beg + 1]; h1 = *(const v8u16*)(H + (size_t)srcS[beg + 1] * C + lane * 8); }
                for (int i = beg + 2; i < end; ++i) {
                    float w2 = exS[i];
                    v8u16 h2 = *(const v8u16*)(H + (size_t)srcS[i] * C + lane * 8);
                    ssum += w0;
#pragma unroll
                    for (int j = 0; j < 8; ++j) acc[j] += w0 * b2f(h0[j]);
                    w0 = w1; h0 = h1; w1 = w2; h1 = h2;
                }
                if (n > 1) {
                    ssum += w0;
#pragma unroll
                    for (int j = 0; j < 8; ++j) acc[j] += w0 * b2f(h0[j]);
                    w0 = w1; h0 = h1;
                }
                ssum += w0;
#pragma unroll
                for (int j = 0; j < 8; ++j) acc[j] += w0 * b2f(h0[j]);
            } else {
                float w0 = exS[beg];
                v4u16 h0 = *(const v4u16*)(H + (size_t)srcS[beg] * C + lane * 4);
                float w1 = 0.f; v4u16 h1{};
                if (n > 1) { w1 = exS[beg + 1]; h1 = *(const v4u16*)(H + (size_t)srcS[beg + 1] * C + lane * 4); }
                for (int i = beg + 2; i < end; ++i) {
                    float w2 = exS[i];
                    v4u16 h2 = *(const v4u16*)(H + (size_t)srcS[i] * C + lane * 4);
                    ssum += w0;
#pragma unroll
                    for (int j = 0; j < 4; ++j) acc[j] += w0 * b2f(h0[j]);
                    w0 = w1; h0 = h1; w1 = w2; h1 = h2;
                }
                if (n > 1) {
                    ssum += w0;
#pragma unroll
                    for (int j = 0; j < 4; ++j) acc[j] += w0 * b2f(h0[j]);
                    w0 = w1; h0 = h1;
                }
                ssum += w0;
#pragma unroll
                for (int j = 0; j < 4; ++j) acc[j] += w0 * b2f(h0[j]);
            }
        }
        float inv = 1.f / (ssum + 1e-16f);
#pragma unroll
        for (int j = 0; j < CV; ++j) out[j] += acc[j] * inv;
    }
    const float* bp = bias + lane * CV;
    u16* gp = G + (size_t)d * C + lane * CV;
    if constexpr (CV == 8) {
        v8u16 o;
#pragma unroll
        for (int j = 0; j < 8; ++j) o[j] = f2b(out[j] + 2.f * bp[j]);
        *(v8u16*)gp = o;
    } else {
        v4u16 o;
#pragma unroll
        for (int j = 0; j < 4; ++j) o[j] = f2b(out[j] + 2.f * bp[j]);
        *(v4u16*)gp = o;
    }
}

// ---------------- MFMA GEMM: 128x128 tile, BK=64, single-buffered 2-barrier,
// global_load_lds width=16 linear LDS dest, T2 bank-swizzle both-sides
// (pre-swizzled global col + swizzled ds_read col; verified 0 conflicts),
// NO XCD swizzle (measured: costs ~8us on this latency-bound shape).
// C[M,N] = A[M,K] @ Bt[N,K]^T. bf16 in, fp32 accum; out bf16 or fp32; bias/relu.
// Optional fused per-row alpha dots: aout_s[row] += sum_col v*avs[col], same d.
__global__ __launch_bounds__(256, 2) void gemm_bf16(
    const u16* __restrict__ A, const u16* __restrict__ Bt, void* __restrict__ Cv,
    int M, int N, int K, const float* __restrict__ bias, int relu, int outf32,
    const float* __restrict__ avs, const float* __restrict__ avd,
    float* __restrict__ aout_s, float* __restrict__ aout_d) {
    __shared__ u16 As[128 * 64];   // [row][64] u16 (col XOR-swizzled), 16 KB
    __shared__ u16 Bs[128 * 64];
    const int tid = threadIdx.x;
    const int lane = tid & 63;
    const int wid = tid >> 6;
    const int wm = wid >> 1;
    const int wn = wid & 1;
    const int quad = lane >> 4;
    const int l16 = lane & 15;
    const int tileM = blockIdx.y * 128;
    const int tileN = blockIdx.x * 128;   // x-fast: same-tileM blocks adjacent

    // staging: inst i covers rows 32i..32i+31 (128B each); thread t ->
    // row = 32i + (t>>3), physical colblock (t&7); LDS dest LINEAR; bank-
    // deswizzle on the GLOBAL source col: logical u16-col = 8*((t&7)^(row&7)).
    const int srow = tid >> 3;                       // 0..31
    const int scol = 8 * ((tid & 7) ^ ((tid >> 3) & 7));
    int ra0 = tileM + srow;       if (ra0 >= M) ra0 = M - 1;
    int ra1 = tileM + 32 + srow;  if (ra1 >= M) ra1 = M - 1;
    int ra2 = tileM + 64 + srow;  if (ra2 >= M) ra2 = M - 1;
    int ra3 = tileM + 96 + srow;  if (ra3 >= M) ra3 = M - 1;
    const u16* gA0 = A + (size_t)ra0 * K + scol;
    const u16* gA1 = A + (size_t)ra1 * K + scol;
    const u16* gA2 = A + (size_t)ra2 * K + scol;
    const u16* gA3 = A + (size_t)ra3 * K + scol;
    const u16* gB0 = Bt + (size_t)(tileN + srow) * K + scol;
    const u16* gB1 = Bt + (size_t)(tileN + 32 + srow) * K + scol;
    const u16* gB2 = Bt + (size_t)(tileN + 64 + srow) * K + scol;
    const u16* gB3 = Bt + (size_t)(tileN + 96 + srow) * K + scol;
    u16* lA0 = As + 0 * 2048 + wid * 512;   // wave-uniform LDS bases (u16)
    u16* lA1 = As + 1 * 2048 + wid * 512;
    u16* lA2 = As + 2 * 2048 + wid * 512;
    u16* lA3 = As + 3 * 2048 + wid * 512;
    u16* lB0 = Bs + 0 * 2048 + wid * 512;
    u16* lB1 = Bs + 1 * 2048 + wid * 512;
    u16* lB2 = Bs + 2 * 2048 + wid * 512;
    u16* lB3 = Bs + 3 * 2048 + wid * 512;

    v4f acc[4][4];
#pragma unroll
    for (int i = 0; i < 4; ++i)
#pragma unroll
        for (int j = 0; j < 4; ++j) acc[i][j] = v4f{0.f, 0.f, 0.f, 0.f};

    for (int k0 = 0; k0 < K; k0 += 64) {
        gll16(gA0 + k0, lA0);
        gll16(gA1 + k0, lA1);
        gll16(gA2 + k0, lA2);
        gll16(gA3 + k0, lA3);
        gll16(gB0 + k0, lB0);
        gll16(gB1 + k0, lB1);
        gll16(gB2 + k0, lB2);
        gll16(gB3 + k0, lB3);
        __syncthreads();
#pragma unroll
        for (int ks = 0; ks < 2; ++ks) {
            // physical col = logical ^ ((row&7)<<3); logical = 8*((ks<<2)|quad)
            const int cblk = ((((ks << 2) | quad) ^ (l16 & 7)) << 3);
            v8bf af[4], bfr[4];
#pragma unroll
            for (int i = 0; i < 4; ++i)
                af[i] = __builtin_bit_cast(v8bf,
                    *(const v8u16*)&As[(wm * 64 + i * 16 + l16) * 64 + cblk]);
#pragma unroll
            for (int i = 0; i < 4; ++i)
                bfr[i] = __builtin_bit_cast(v8bf,
                    *(const v8u16*)&Bs[(wn * 64 + i * 16 + l16) * 64 + cblk]);
#pragma unroll
            for (int mi = 0; mi < 4; ++mi)
#pragma unroll
                for (int ni = 0; ni < 4; ++ni)
                    acc[mi][ni] = __builtin_amdgcn_mfma_f32_16x16x32_bf16(af[mi], bfr[ni], acc[mi][ni], 0, 0, 0);
        }
        __syncthreads();
    }

    float rs[4][4], rd[4][4];
#pragma unroll
    for (int mi = 0; mi < 4; ++mi)
#pragma unroll
        for (int rr = 0; rr < 4; ++rr) { rs[mi][rr] = 0.f; rd[mi][rr] = 0.f; }

#pragma unroll
    for (int mi = 0; mi < 4; ++mi)
#pragma unroll
        for (int ni = 0; ni < 4; ++ni) {
            int col = tileN + wn * 64 + ni * 16 + l16;
            float bb = bias ? bias[col] : 0.f;
            float ws_ = avs ? avs[col] : 0.f;
            float wd_ = avd ? avd[col] : 0.f;
            int row0 = tileM + wm * 64 + mi * 16 + quad * 4;
#pragma unroll
            for (int rr = 0; rr < 4; ++rr) {
                int row = row0 + rr;
                if (row < M) {
                    float v = acc[mi][ni][rr] + bb;
                    if (relu) v = fmaxf(v, 0.f);
                    if (outf32) ((float*)Cv)[(size_t)row * N + col] = v;
                    else        ((u16*)Cv)[(size_t)row * N + col] = f2b(v);
                    rs[mi][rr] += v * ws_;
                    rd[mi][rr] += v * wd_;
                }
            }
        }

    if (avs) {   // fused alpha: reduce 16 col-lanes per quad, one atomic per row
#pragma unroll
        for (int mi = 0; mi < 4; ++mi)
#pragma unroll
            for (int rr = 0; rr < 4; ++rr) {
                int row = tileM + wm * 64 + mi * 16 + quad * 4 + rr;
                float a = rs[mi][rr], b = rd[mi][rr];
                a += __shfl_down(a, 8, 64); a += __shfl_down(a, 4, 64);
                a += __shfl_down(a, 2, 64); a += __shfl_down(a, 1, 64);
                b += __shfl_down(b, 8, 64); b += __shfl_down(b, 4, 64);
                b += __shfl_down(b, 2, 64); b += __shfl_down(b, 1, 64);
                if (l16 == 0 && row < M) {
                    atomicAdd(&aout_s[row], a);
                    atomicAdd(&aout_d[row], b);
                }
            }
    }
}

// ---------------- launch ----------------

extern "C" void kernel_launch(void* const* d_in, const int* in_sizes, int n_in,
                              void* d_out, int out_size, void* d_ws, size_t ws_size,
                              hipStream_t stream) {
    const float* x  = (const float*)d_in[0];
    const int* ei1  = (const int*)d_in[1];
    const int* ei2  = (const int*)d_in[2];
    const float* W1s = (const float*)d_in[3];
    const float* W1d = (const float*)d_in[4];
    const float* a1s = (const float*)d_in[5];
    const float* a1d = (const float*)d_in[6];
    const float* b1  = (const float*)d_in[7];
    const float* Wl1 = (const float*)d_in[8];
    const float* bl1 = (const float*)d_in[9];
    const float* W2s = (const float*)d_in[10];
    const float* W2d = (const float*)d_in[11];
    const float* a2s = (const float*)d_in[12];
    const float* a2d = (const float*)d_in[13];
    const float* b2  = (const float*)d_in[14];
    const float* Wl2 = (const float*)d_in[15];
    const float* bl2 = (const float*)d_in[16];
    float* out = (float*)d_out;

    char* ws = (char*)d_ws;
    size_t off = 0;
    auto alloc = [&](size_t b) { void* p = ws + off; off = (off + b + 255) & ~(size_t)255; return p; };
    u16* bufA   = (u16*)alloc((size_t)NN * 512 * 2);   // Hsrc1 -> hmid
    u16* bufB   = (u16*)alloc((size_t)NN * 512 * 2);   // xb16 -> g1 -> Hsrc2(lo)+g2(hi)
    int* rp     = (int*)alloc((size_t)2 * (NN + 1) * 4);
    int* srcp   = (int*)alloc((size_t)2 * EE * 4);
    int* dstp   = (int*)alloc((size_t)2 * EE * 4);
    int* deg    = (int*)alloc((size_t)2 * NN * 4);
    int* bsum   = (int*)alloc((size_t)2 * NB_PER_SET * 4);
    float* ex   = (float*)alloc((size_t)2 * EE * 4);
    float* asrc = (float*)alloc((size_t)NN * 4);
    float* adst = (float*)alloc((size_t)NN * 4);
    float* vbuf = (float*)alloc(2048 * 4);             // v1s|v1d|v2s|v2d
    u16* Wt1s   = (u16*)alloc((size_t)512 * 512 * 2);
    u16* Wtl1   = (u16*)alloc((size_t)512 * 512 * 2);
    u16* Wt2s   = (u16*)alloc((size_t)512 * 256 * 2);
    u16* Wtl2   = (u16*)alloc((size_t)256 * 256 * 2);
    u16* g2buf  = bufB + (size_t)NN * 256;

    // CSR build (both sets)
    hipMemsetAsync(deg, 0, (size_t)2 * NN * 4, stream);
    deg2_kernel<<<(2 * EE + 255) / 256, 256, 0, stream>>>(ei1, ei2, deg);
    scan_partial<<<2 * NB_PER_SET, 256, 0, stream>>>(deg, bsum);
    scan_tops<<<1, 256, 0, stream>>>(bsum);
    scan_final<<<2 * NB_PER_SET, 256, 0, stream>>>(deg, bsum, rp);
    fill2_kernel<<<(2 * EE + 255) / 256, 256, 0, stream>>>(ei1, ei2, rp, deg, srcp, dstp);

    // weight prep
    transpose4t<<<704, 256, 0, stream>>>(W1s, Wt1s, Wl1, Wtl1, W2s, Wt2s, Wl2, Wtl2);
    wv4<<<512, 256, 0, stream>>>(W1s, W1d, W2s, W2d, a1s, a1d, a2s, a2d, vbuf);

    // ---- layer 1 ----
    alpha_pair_f32x<<<(NN + 3) / 4, 256, 0, stream>>>(x, vbuf, vbuf + 512, asrc, adst, bufB, NN);
    edge_ex<<<(2 * EE + 255) / 256, 256, 0, stream>>>(srcp, dstp, asrc, adst, ex);
    gemm_bf16<<<dim3(4, 391), 256, 0, stream>>>(bufB, Wt1s, bufA, NN, 512, 512, nullptr, 0, 0,
                                                nullptr, nullptr, nullptr, nullptr);
    // gat_pull also zeroes asrc/adst for the fused layer-2 alpha accumulation
    gat_pull<8><<<(NN + 3) / 4, 256, 0, stream>>>(rp, srcp, ex, bufA, b1, bufB, NN, asrc, adst);
    gemm_bf16<<<dim3(4, 391), 256, 0, stream>>>(bufB, Wtl1, bufA, NN, 512, 512, bl1, 1, 0,
                                                vbuf + 1024, vbuf + 1536, asrc, adst);

    // ---- layer 2 ----
    edge_ex<<<(2 * EE + 255) / 256, 256, 0, stream>>>(srcp, dstp, asrc, adst, ex);
    gemm_bf16<<<dim3(2, 391), 256, 0, stream>>>(bufA, Wt2s, bufB, NN, 256, 512, nullptr, 0, 0,
                                                nullptr, nullptr, nullptr, nullptr);
    gat_pull<4><<<(NN + 3) / 4, 256, 0, stream>>>(rp, srcp, ex, bufB, b2, g2buf, NN, nullptr, nullptr);
    gemm_bf16<<<dim3(2, 391), 256, 0, stream>>>(g2buf, Wtl2, out, NN, 256, 256, bl2, 0, 1,
                                                nullptr, nullptr, nullptr, nullptr);

    (void)in_sizes; (void)n_in; (void)out_size; (void)ws_size;
}